// Round 10
// baseline (319.721 us; speedup 1.0000x reference)
//
#include <hip/hip_runtime.h>
#include <hip/hip_bf16.h>
#include <cstdint>
#include <cstddef>

// Problem constants
constexpr int B_  = 2;
constexpr int S_  = 4096;
constexpr int D_  = 1024;
constexpr int H_  = 16;
constexpr int DH_ = 64;
constexpr int DIL = 4;
constexpr int L_  = S_ / DIL;  // 1024
constexpr int M_  = B_ * S_;   // 8192

typedef __attribute__((ext_vector_type(8))) short short8;
typedef __attribute__((ext_vector_type(4))) float f32x4;

__device__ __forceinline__ unsigned short f2b(float f) {
    union { float f; unsigned u; } v;
    v.f = f;
    unsigned r = v.u + 0x7fff + ((v.u >> 16) & 1);   // RNE
    return (unsigned short)(r >> 16);
}

__device__ __forceinline__ unsigned pkbf(float a, float b) {
    float2 t; t.x = a; t.y = b;
    __hip_bfloat162 h = __float22bfloat162_rn(t);    // v_cvt_pk_bf16_f32
    union { __hip_bfloat162 h; unsigned u; } c; c.h = h;
    return c.u;
}

// m204 bijective XCD swizzle (8 XCDs)
__device__ __forceinline__ int xcd_swz(int orig, int nwg) {
    int q = nwg >> 3, r = nwg & 7;
    int xcd = orig & 7, idx = orig >> 3;
    return (xcd < r ? xcd * (q + 1) : r * (q + 1) + (xcd - r) * q) + idx;
}

#define GLOAD16(gptr, lptr)                                                    \
    __builtin_amdgcn_global_load_lds(                                          \
        (const __attribute__((address_space(1))) void*)(gptr),                 \
        (__attribute__((address_space(3))) void*)(lptr), 16, 0, 0)

// ---------------------------------------------------------------------------
// fp32 -> bf16 converts
// ---------------------------------------------------------------------------
__global__ __launch_bounds__(256)
void conv_f2b(const float* __restrict__ in, unsigned short* __restrict__ out, int n4) {
    int i = blockIdx.x * 256 + threadIdx.x;
    if (i < n4) {
        float4 v = reinterpret_cast<const float4*>(in)[i];
        ushort4 o;
        o.x = f2b(v.x); o.y = f2b(v.y); o.z = f2b(v.z); o.w = f2b(v.w);
        reinterpret_cast<ushort4*>(out)[i] = o;
    }
}

// all four weight matrices in one launch (1024 blocks each)
__global__ __launch_bounds__(256)
void conv_w4(const float* __restrict__ w0, const float* __restrict__ w1,
             const float* __restrict__ w2, const float* __restrict__ w3,
             unsigned short* __restrict__ out) {
    int bid = blockIdx.x;
    int which = bid >> 10;
    const float* src = (which == 0) ? w0 : (which == 1) ? w1 : (which == 2) ? w2 : w3;
    int i = (bid & 1023) * 256 + threadIdx.x;
    float4 v = reinterpret_cast<const float4*>(src)[i];
    ushort4 o;
    o.x = f2b(v.x); o.y = f2b(v.y); o.z = f2b(v.z); o.w = f2b(v.w);
    reinterpret_cast<ushort4*>(out + (size_t)which * D_ * D_)[i] = o;
}

// ---------------------------------------------------------------------------
// MFMA GEMM, 2-phase double-buffered (T3-minimum): stage(k+1) issued BEFORE
// compute(k); single vmcnt-draining barrier per K-step -> load latency hides
// under ds_read+MFMA. BM=BN=128, BK=64, 4 waves; bn-fast XCD mapping.
// ---------------------------------------------------------------------------
template <int OUT_BF16>
__global__ __launch_bounds__(256)
void gemm_mfma(const unsigned short* __restrict__ A,
               const unsigned short* __restrict__ W,
               const float* __restrict__ bias,
               void* __restrict__ Cout, int M, int N, int K) {
    __shared__ unsigned short As[2][128 * 64];
    __shared__ unsigned short Bs[2][128 * 64];

    const int tid  = threadIdx.x;
    const int lane = tid & 63, wave = tid >> 6;
    const int l15 = lane & 15, l4 = lane >> 4;
    const int wr = wave >> 1, wc = wave & 1;
    const int gx = N >> 7;
    const int wg = xcd_swz(blockIdx.x, gridDim.x);
    const int bm = (wg / gx) * 128, bn = (wg % gx) * 128;

    auto stage = [&](int k0, int buf) {
        #pragma unroll
        for (int i = 0; i < 4; ++i) {
            int ch = i * 256 + wave * 64 + lane;
            int r = ch >> 3, c8 = ch & 7;
            const unsigned short* ga = A + (size_t)(bm + r) * K + k0 + c8 * 8;
            GLOAD16(ga, (char*)&As[buf][0] + (size_t)(i * 256 + wave * 64) * 16);
            const unsigned short* gb = W + (size_t)(bn + r) * K + k0 + c8 * 8;
            GLOAD16(gb, (char*)&Bs[buf][0] + (size_t)(i * 256 + wave * 64) * 16);
        }
    };

    f32x4 acc[4][4] = {};

    stage(0, 0);
    __syncthreads();
    int cur = 0;

    for (int k0 = 0; k0 < K; k0 += 64) {
        if (k0 + 64 < K) stage(k0 + 64, cur ^ 1);   // in flight during compute

        #pragma unroll
        for (int ks = 0; ks < 2; ++ks) {
            short8 af[4], bf[4];
            #pragma unroll
            for (int mi = 0; mi < 4; ++mi)
                af[mi] = *reinterpret_cast<const short8*>(
                    &As[cur][(wr * 64 + mi * 16 + l15) * 64 + ks * 32 + l4 * 8]);
            #pragma unroll
            for (int ni = 0; ni < 4; ++ni)
                bf[ni] = *reinterpret_cast<const short8*>(
                    &Bs[cur][(wc * 64 + ni * 16 + l15) * 64 + ks * 32 + l4 * 8]);
            #pragma unroll
            for (int mi = 0; mi < 4; ++mi)
                #pragma unroll
                for (int ni = 0; ni < 4; ++ni)
                    acc[mi][ni] = __builtin_amdgcn_mfma_f32_16x16x32_bf16(
                        af[mi], bf[ni], acc[mi][ni], 0, 0, 0);
        }
        __syncthreads();   // drains staged loads; protects cur for next write
        cur ^= 1;
    }

    #pragma unroll
    for (int ni = 0; ni < 4; ++ni) {
        int col = bn + wc * 64 + ni * 16 + l15;
        float bv = bias[col];
        #pragma unroll
        for (int mi = 0; mi < 4; ++mi) {
            #pragma unroll
            for (int r = 0; r < 4; ++r) {
                int row = bm + wr * 64 + mi * 16 + l4 * 4 + r;
                float v = acc[mi][ni][r] + bv;
                if (OUT_BF16)
                    ((unsigned short*)Cout)[(size_t)row * N + col] = f2b(v);
                else
                    ((float*)Cout)[(size_t)row * N + col] = v;
            }
        }
    }
}

// ---------------------------------------------------------------------------
// Fused QKV GEMM, 2-phase double-buffered; W = [Wq;Wk;Wv] [3072][1024].
// Q segment pre-scaled by 1/sqrt(dh) = 0.125 (exact pow2).
// ---------------------------------------------------------------------------
__global__ __launch_bounds__(256)
void gemm_qkv(const unsigned short* __restrict__ A,
              const unsigned short* __restrict__ W,
              const float* __restrict__ bq, const float* __restrict__ bk,
              const float* __restrict__ bv,
              unsigned short* __restrict__ Qb, unsigned short* __restrict__ Kb,
              unsigned short* __restrict__ Vb, int M, int K) {
    __shared__ unsigned short As[2][128 * 64];
    __shared__ unsigned short Bs[2][128 * 64];

    const int tid  = threadIdx.x;
    const int lane = tid & 63, wave = tid >> 6;
    const int l15 = lane & 15, l4 = lane >> 4;
    const int wr = wave >> 1, wc = wave & 1;
    const int gx = 24;   // 3072 / 128
    const int wg = xcd_swz(blockIdx.x, gridDim.x);
    const int bm = (wg / gx) * 128, bn = (wg % gx) * 128;

    auto stage = [&](int k0, int buf) {
        #pragma unroll
        for (int i = 0; i < 4; ++i) {
            int ch = i * 256 + wave * 64 + lane;
            int r = ch >> 3, c8 = ch & 7;
            const unsigned short* ga = A + (size_t)(bm + r) * K + k0 + c8 * 8;
            GLOAD16(ga, (char*)&As[buf][0] + (size_t)(i * 256 + wave * 64) * 16);
            const unsigned short* gb = W + (size_t)(bn + r) * K + k0 + c8 * 8;
            GLOAD16(gb, (char*)&Bs[buf][0] + (size_t)(i * 256 + wave * 64) * 16);
        }
    };

    f32x4 acc[4][4] = {};

    stage(0, 0);
    __syncthreads();
    int cur = 0;

    for (int k0 = 0; k0 < K; k0 += 64) {
        if (k0 + 64 < K) stage(k0 + 64, cur ^ 1);

        #pragma unroll
        for (int ks = 0; ks < 2; ++ks) {
            short8 af[4], bf[4];
            #pragma unroll
            for (int mi = 0; mi < 4; ++mi)
                af[mi] = *reinterpret_cast<const short8*>(
                    &As[cur][(wr * 64 + mi * 16 + l15) * 64 + ks * 32 + l4 * 8]);
            #pragma unroll
            for (int ni = 0; ni < 4; ++ni)
                bf[ni] = *reinterpret_cast<const short8*>(
                    &Bs[cur][(wc * 64 + ni * 16 + l15) * 64 + ks * 32 + l4 * 8]);
            #pragma unroll
            for (int mi = 0; mi < 4; ++mi)
                #pragma unroll
                for (int ni = 0; ni < 4; ++ni)
                    acc[mi][ni] = __builtin_amdgcn_mfma_f32_16x16x32_bf16(
                        af[mi], bf[ni], acc[mi][ni], 0, 0, 0);
        }
        __syncthreads();
        cur ^= 1;
    }

    const int seg = bn >> 10;                 // 0=Q 1=K 2=V
    const float* bp = (seg == 0) ? bq : (seg == 1) ? bk : bv;
    unsigned short* ob = (seg == 0) ? Qb : (seg == 1) ? Kb : Vb;
    const float qs = (seg == 0) ? 0.125f : 1.0f;   // fold 1/sqrt(dh) into Q
    const int cb = bn & 1023;

    #pragma unroll
    for (int ni = 0; ni < 4; ++ni) {
        int col = cb + wc * 64 + ni * 16 + l15;
        float bvv = bp[col];
        #pragma unroll
        for (int mi = 0; mi < 4; ++mi) {
            #pragma unroll
            for (int r = 0; r < 4; ++r) {
                int row = bm + wr * 64 + mi * 16 + l4 * 4 + r;
                ob[(size_t)row * 1024 + col] = f2b((acc[mi][ni][r] + bvv) * qs);
            }
        }
    }
}

// ---------------------------------------------------------------------------
// V transpose prepass: Vb [m][1024] bf16 -> Vtg [(bd*16+h)*64 + dh][L] bf16.
// ---------------------------------------------------------------------------
__global__ __launch_bounds__(256)
void tvt(const unsigned short* __restrict__ Vb, unsigned short* __restrict__ Vtg) {
    __shared__ unsigned short Ts[64 * 64];
    const int tid = threadIdx.x;
    const int blk = blockIdx.x;
    const int lt = blk & 15;
    const int h  = (blk >> 4) & 15;
    const int bd = blk >> 8;
    const int b = bd >> 2, dd = bd & 3;
    const size_t rowbase = (size_t)b * S_;

    #pragma unroll
    for (int i = 0; i < 2; ++i) {
        int ch = i * 256 + tid;
        int lloc = ch >> 3, c8 = ch & 7;
        short8 v = *reinterpret_cast<const short8*>(
            Vb + (rowbase + (size_t)(lt * 64 + lloc) * DIL + dd) * D_ + h * 64 + c8 * 8);
        #pragma unroll
        for (int j = 0; j < 8; ++j) {
            int dh = c8 * 8 + j;
            Ts[dh * 64 + (((lloc >> 3) ^ (dh & 7)) * 8) + (lloc & 7)] = (unsigned short)v[j];
        }
    }
    __syncthreads();

    const size_t obase = ((size_t)(bd * 16 + h) * 64) * L_;
    #pragma unroll
    for (int i = 0; i < 2; ++i) {
        int ch = i * 256 + tid;
        int dh = ch >> 3, c = ch & 7;
        uint4 val = *reinterpret_cast<const uint4*>(&Ts[dh * 64 + ((c ^ (dh & 7)) * 8)]);
        *reinterpret_cast<uint4*>(Vtg + obase + (size_t)dh * L_ + lt * 64 + c * 8) = val;
    }
}

// ---------------------------------------------------------------------------
// MFMA flash attention, swapped-operand form (Q pre-scaled by 0.125).
// ---------------------------------------------------------------------------
__global__ __launch_bounds__(256)
void attn_mfma(const unsigned short* __restrict__ Q,
               const unsigned short* __restrict__ K,
               const unsigned short* __restrict__ Vtg,
               unsigned short* __restrict__ O) {
    __shared__ unsigned short Ks[2][64 * 64];   // [key][chunk ^ (key&7)]
    __shared__ unsigned short Vs[2][64 * 64];   // V^T [dh][chunk ^ (dh&7)]
    __shared__ unsigned short Ps[4][1024];      // per-wave P band [q=16][key=64]

    const int tid = threadIdx.x;
    const int lane = tid & 63, wave = tid >> 6;
    const int l15 = lane & 15, l4 = lane >> 4;
    const int blk = xcd_swz(blockIdx.x, gridDim.x);
    const int qt = blk & 15;
    const int h  = (blk >> 4) & 15;
    const int bd = blk >> 8;
    const int b = bd >> 2, dd = bd & 3;
    const size_t rowbase = (size_t)b * S_;
    const int colbase = h * DH_;

    short8 qf[2];
    {
        int q = qt * 64 + wave * 16 + l15;
        const unsigned short* qp =
            Q + (rowbase + (size_t)q * DIL + dd) * D_ + colbase;
        qf[0] = *reinterpret_cast<const short8*>(qp + l4 * 8);
        qf[1] = *reinterpret_cast<const short8*>(qp + 32 + l4 * 8);
    }

    const unsigned short* vbase = Vtg + ((size_t)(bd * 16 + h) * 64) * L_;

    auto stageK = [&](int kt, int buf) {
        #pragma unroll
        for (int i = 0; i < 2; ++i) {
            int key = i * 32 + wave * 8 + (lane >> 3);
            int srcc = (lane & 7) ^ (lane >> 3);      // pre-swizzled source chunk
            const unsigned short* g =
                K + (rowbase + (size_t)(kt * 64 + key) * DIL + dd) * D_ + colbase + srcc * 8;
            GLOAD16(g, (char*)&Ks[buf][0] + (size_t)(i * 256 + wave * 64) * 16);
        }
    };
    auto stageV = [&](int kt, int buf) {
        #pragma unroll
        for (int i = 0; i < 2; ++i) {
            int dh = i * 32 + wave * 8 + (lane >> 3);
            int srcc = (lane & 7) ^ (lane >> 3);
            const unsigned short* g = vbase + (size_t)dh * L_ + kt * 64 + srcc * 8;
            GLOAD16(g, (char*)&Vs[buf][0] + (size_t)(i * 256 + wave * 64) * 16);
        }
    };

    f32x4 oT[4] = {};
    float m_run = -1e30f, l_run = 0.f;

    stageK(0, 0);
    stageV(0, 0);
    __syncthreads();

    constexpr int NT = L_ / 64;
    for (int kt = 0; kt < NT; ++kt) {
        int cur = kt & 1, nxt = cur ^ 1;
        if (kt < NT - 1) {                 // issue next-tile staging early
            stageK(kt + 1, nxt);
            stageV(kt + 1, nxt);
        }

        // ---- QK^T (S^T form): lane holds S[q=l15][key = n*16 + l4*4 + r] ----
        f32x4 sT[4];
        #pragma unroll
        for (int n = 0; n < 4; ++n) {
            int row = n * 16 + l15;
            short8 kf0 = *reinterpret_cast<const short8*>(
                &Ks[cur][row * 64 + ((0 * 4 + l4) ^ (l15 & 7)) * 8]);
            short8 kf1 = *reinterpret_cast<const short8*>(
                &Ks[cur][row * 64 + ((1 * 4 + l4) ^ (l15 & 7)) * 8]);
            f32x4 z = {0.f, 0.f, 0.f, 0.f};
            z = __builtin_amdgcn_mfma_f32_16x16x32_bf16(kf0, qf[0], z, 0, 0, 0);
            z = __builtin_amdgcn_mfma_f32_16x16x32_bf16(kf1, qf[1], z, 0, 0, 0);
            sT[n] = z;   // Q pre-scaled by 1/sqrt(dh)
        }

        // ---- lane-local online softmax (q = l15) ----
        float mx = -1e30f;
        #pragma unroll
        for (int n = 0; n < 4; ++n)
            #pragma unroll
            for (int r = 0; r < 4; ++r) mx = fmaxf(mx, sT[n][r]);
        mx = fmaxf(mx, __shfl_xor(mx, 16));
        mx = fmaxf(mx, __shfl_xor(mx, 32));
        float m_new = fmaxf(m_run, mx);
        float scale = __expf(m_run - m_new);
        float p[4][4], rsum = 0.f;
        #pragma unroll
        for (int n = 0; n < 4; ++n)
            #pragma unroll
            for (int r = 0; r < 4; ++r) {
                p[n][r] = __expf(sT[n][r] - m_new);
                rsum += p[n][r];
            }
        rsum += __shfl_xor(rsum, 16);
        rsum += __shfl_xor(rsum, 32);
        l_run = l_run * scale + rsum;
        m_run = m_new;
        #pragma unroll
        for (int nd = 0; nd < 4; ++nd) oT[nd] *= scale;

        // ---- P -> per-wave swizzled LDS band ----
        #pragma unroll
        for (int n = 0; n < 4; ++n) {
            uint2 w;
            w.x = pkbf(p[n][0], p[n][1]);
            w.y = pkbf(p[n][2], p[n][3]);
            int c = n * 2 + (l4 >> 1);
            int pc = c ^ (l15 & 7);
            *reinterpret_cast<uint2*>(&Ps[wave][l15 * 64 + pc * 8 + (l4 & 1) * 4]) = w;
        }
        short8 pb0 = *reinterpret_cast<const short8*>(
            &Ps[wave][l15 * 64 + ((0 * 4 + l4) ^ (l15 & 7)) * 8]);
        short8 pb1 = *reinterpret_cast<const short8*>(
            &Ps[wave][l15 * 64 + ((1 * 4 + l4) ^ (l15 & 7)) * 8]);

        // ---- PV: O^T += V^T . P ----
        #pragma unroll
        for (int ks = 0; ks < 2; ++ks) {
            short8 pb = ks ? pb1 : pb0;
            #pragma unroll
            for (int nd = 0; nd < 4; ++nd) {
                short8 vf = *reinterpret_cast<const short8*>(
                    &Vs[cur][(nd * 16 + l15) * 64 + ((ks * 4 + l4) ^ (l15 & 7)) * 8]);
                oT[nd] = __builtin_amdgcn_mfma_f32_16x16x32_bf16(vf, pb, oT[nd], 0, 0, 0);
            }
        }

        __syncthreads();   // next-tile staging complete + buffers protected
    }

    // ---- epilogue: per-wave transpose band (reuse Ps) + coalesced store ----
    unsigned short* Es = &Ps[0][0];
    float inv = 1.f / l_run;
    #pragma unroll
    for (int nd = 0; nd < 4; ++nd) {
        uint2 w;
        w.x = pkbf(oT[nd][0] * inv, oT[nd][1] * inv);
        w.y = pkbf(oT[nd][2] * inv, oT[nd][3] * inv);
        int chunk = nd * 2 + (l4 >> 1);
        int pc = chunk ^ (l15 & 7);
        *reinterpret_cast<uint2*>(&Es[wave * 1024 + l15 * 64 + pc * 8 + (l4 & 1) * 4]) = w;
    }
    __syncthreads();
    {
        int row = lane >> 2;              // q_local 0..15
        int q = qt * 64 + wave * 16 + row;
        unsigned short* op = O + (rowbase + (size_t)q * DIL + dd) * D_ + colbase;
        #pragma unroll
        for (int i = 0; i < 2; ++i) {
            int c = (lane & 3) * 2 + i;
            int pc = c ^ (row & 7);
            uint4 val = *reinterpret_cast<const uint4*>(&Es[wave * 1024 + row * 64 + pc * 8]);
            *reinterpret_cast<uint4*>(op + c * 8) = val;
        }
    }
}

// ---------------------------------------------------------------------------
// final = LayerNorm(atted + x) * gamma + beta
// ---------------------------------------------------------------------------
__global__ __launch_bounds__(256)
void add_ln(const float* __restrict__ atted, const float* __restrict__ x,
            const float* __restrict__ gamma, const float* __restrict__ beta,
            float* __restrict__ out) {
    __shared__ float red[8];
    const int tid = threadIdx.x;
    const size_t base = (size_t)blockIdx.x * D_;

    float4 a  = *reinterpret_cast<const float4*>(atted + base + tid * 4);
    float4 xv = *reinterpret_cast<const float4*>(x + base + tid * 4);
    float v0 = a.x + xv.x, v1 = a.y + xv.y, v2 = a.z + xv.z, v3 = a.w + xv.w;

    float s = v0 + v1 + v2 + v3;
    #pragma unroll
    for (int o = 1; o < 64; o <<= 1) s += __shfl_xor(s, o);
    if ((tid & 63) == 0) red[tid >> 6] = s;
    __syncthreads();
    float mean = (red[0] + red[1] + red[2] + red[3]) * (1.0f / D_);

    float d0 = v0 - mean, d1 = v1 - mean, d2 = v2 - mean, d3 = v3 - mean;
    float sq = d0 * d0 + d1 * d1 + d2 * d2 + d3 * d3;
    #pragma unroll
    for (int o = 1; o < 64; o <<= 1) sq += __shfl_xor(sq, o);
    if ((tid & 63) == 0) red[4 + (tid >> 6)] = sq;
    __syncthreads();
    float var = (red[4] + red[5] + red[6] + red[7]) * (1.0f / D_);
    float inv = rsqrtf(var + 1e-5f);

    float4 g  = *reinterpret_cast<const float4*>(gamma + tid * 4);
    float4 bb = *reinterpret_cast<const float4*>(beta + tid * 4);
    float4 o4;
    o4.x = d0 * inv * g.x + bb.x;
    o4.y = d1 * inv * g.y + bb.y;
    o4.z = d2 * inv * g.z + bb.z;
    o4.w = d3 * inv * g.w + bb.w;
    *reinterpret_cast<float4*>(out + base + tid * 4) = o4;
}

// ---------------------------------------------------------------------------
extern "C" void kernel_launch(void* const* d_in, const int* in_sizes, int n_in,
                              void* d_out, int out_size, void* d_ws, size_t ws_size,
                              hipStream_t stream) {
    const float* x     = (const float*)d_in[0];
    const float* Wq    = (const float*)d_in[1];
    const float* bq    = (const float*)d_in[2];
    const float* Wk    = (const float*)d_in[3];
    const float* bk    = (const float*)d_in[4];
    const float* Wv    = (const float*)d_in[5];
    const float* bv    = (const float*)d_in[6];
    const float* Wf    = (const float*)d_in[7];
    const float* bf    = (const float*)d_in[8];
    const float* gamma = (const float*)d_in[9];
    const float* beta  = (const float*)d_in[10];

    float* final_out = (float*)d_out;               // (B,S,D) fp32
    float* atted     = final_out + (size_t)M_ * D_; // (B,S,D) fp32

    // Workspace (bf16): 16 + 8 + 48 + 16 = 88 MB (<100.7 MB proven in R1)
    unsigned short* xb  = (unsigned short*)d_ws;    // reused as ctxb after QKV
    unsigned short* Wqb = xb  + (size_t)M_ * D_;
    unsigned short* Wkb = Wqb + (size_t)D_ * D_;
    unsigned short* Wvb = Wkb + (size_t)D_ * D_;
    unsigned short* Wfb = Wvb + (size_t)D_ * D_;
    unsigned short* Qb  = Wfb + (size_t)D_ * D_;
    unsigned short* Kb  = Qb  + (size_t)M_ * D_;
    unsigned short* Vb  = Kb  + (size_t)M_ * D_;
    unsigned short* Vtg = Vb  + (size_t)M_ * D_;    // [(bd*16+h)*64+dh][L]
    unsigned short* ctxb = xb;

    conv_f2b<<<dim3(M_ * D_ / 4 / 256), 256, 0, stream>>>(x, xb, M_ * D_ / 4);
    conv_w4<<<dim3(4096), 256, 0, stream>>>(Wq, Wk, Wv, Wf, Wqb);

    gemm_qkv<<<dim3((3072 / 128) * (M_ / 128)), 256, 0, stream>>>(
        xb, Wqb, bq, bk, bv, Qb, Kb, Vb, M_, D_);

    tvt<<<dim3(DIL * B_ * H_ * (L_ / 64)), 256, 0, stream>>>(Vb, Vtg);

    attn_mfma<<<dim3(DIL * B_ * H_ * (L_ / 64)), 256, 0, stream>>>(Qb, Kb, Vtg, ctxb);

    gemm_mfma<0><<<dim3((D_ / 128) * (M_ / 128)), 256, 0, stream>>>(
        ctxb, Wfb, bf, atted, M_, D_, D_);

    add_ln<<<dim3(M_), 256, 0, stream>>>(atted, x, gamma, beta, final_out);
}

// Round 12
// 304.101 us; speedup vs baseline: 1.0514x; 1.0514x over previous
//
#include <hip/hip_runtime.h>
#include <hip/hip_bf16.h>
#include <cstdint>
#include <cstddef>

// Problem constants
constexpr int B_  = 2;
constexpr int S_  = 4096;
constexpr int D_  = 1024;
constexpr int H_  = 16;
constexpr int DH_ = 64;
constexpr int DIL = 4;
constexpr int L_  = S_ / DIL;  // 1024
constexpr int M_  = B_ * S_;   // 8192

typedef __attribute__((ext_vector_type(8))) short short8;
typedef __attribute__((ext_vector_type(4))) float f32x4;

__device__ __forceinline__ unsigned short f2b(float f) {
    union { float f; unsigned u; } v;
    v.f = f;
    unsigned r = v.u + 0x7fff + ((v.u >> 16) & 1);   // RNE
    return (unsigned short)(r >> 16);
}

__device__ __forceinline__ unsigned pkbf(float a, float b) {
    float2 t; t.x = a; t.y = b;
    __hip_bfloat162 h = __float22bfloat162_rn(t);    // v_cvt_pk_bf16_f32
    union { __hip_bfloat162 h; unsigned u; } c; c.h = h;
    return c.u;
}

// m204 bijective XCD swizzle (8 XCDs)
__device__ __forceinline__ int xcd_swz(int orig, int nwg) {
    int q = nwg >> 3, r = nwg & 7;
    int xcd = orig & 7, idx = orig >> 3;
    return (xcd < r ? xcd * (q + 1) : r * (q + 1) + (xcd - r) * q) + idx;
}

#define GLOAD16(gptr, lptr)                                                    \
    __builtin_amdgcn_global_load_lds(                                          \
        (const __attribute__((address_space(1))) void*)(gptr),                 \
        (__attribute__((address_space(3))) void*)(lptr), 16, 0, 0)

// counted-vmcnt wait (T4): keep N newest vmem ops in flight, drain older
#define VMCNT(N) asm volatile("s_waitcnt vmcnt(" #N ")" ::: "memory")

// ---------------------------------------------------------------------------
// fp32 -> bf16 converts
// ---------------------------------------------------------------------------
__global__ __launch_bounds__(256)
void conv_f2b(const float* __restrict__ in, unsigned short* __restrict__ out, int n4) {
    int i = blockIdx.x * 256 + threadIdx.x;
    if (i < n4) {
        float4 v = reinterpret_cast<const float4*>(in)[i];
        ushort4 o;
        o.x = f2b(v.x); o.y = f2b(v.y); o.z = f2b(v.z); o.w = f2b(v.w);
        reinterpret_cast<ushort4*>(out)[i] = o;
    }
}

// all four weight matrices in one launch (1024 blocks each)
__global__ __launch_bounds__(256)
void conv_w4(const float* __restrict__ w0, const float* __restrict__ w1,
             const float* __restrict__ w2, const float* __restrict__ w3,
             unsigned short* __restrict__ out) {
    int bid = blockIdx.x;
    int which = bid >> 10;
    const float* src = (which == 0) ? w0 : (which == 1) ? w1 : (which == 2) ? w2 : w3;
    int i = (bid & 1023) * 256 + threadIdx.x;
    float4 v = reinterpret_cast<const float4*>(src)[i];
    ushort4 o;
    o.x = f2b(v.x); o.y = f2b(v.y); o.z = f2b(v.z); o.w = f2b(v.w);
    reinterpret_cast<ushort4*>(out + (size_t)which * D_ * D_)[i] = o;
}

// ---------------------------------------------------------------------------
// MFMA GEMM with counted-vmcnt pipeline (T3+T4):
//   stage(k+1) -> vmcnt(8) [tile k done, tile k+1 stays in flight]
//   -> s_barrier -> ds_read+MFMA -> s_barrier.
// Loads are never drained to 0 inside the loop (the m97-structure stall).
// BM=BN=128, BK=64, 4 waves; bn-fast XCD mapping.
// ---------------------------------------------------------------------------
template <int OUT_BF16>
__global__ __launch_bounds__(256)
void gemm_mfma(const unsigned short* __restrict__ A,
               const unsigned short* __restrict__ W,
               const float* __restrict__ bias,
               void* __restrict__ Cout, int M, int N, int K) {
    __shared__ unsigned short As[2][128 * 64];
    __shared__ unsigned short Bs[2][128 * 64];

    const int tid  = threadIdx.x;
    const int lane = tid & 63, wave = tid >> 6;
    const int l15 = lane & 15, l4 = lane >> 4;
    const int wr = wave >> 1, wc = wave & 1;
    const int gx = N >> 7;
    const int wg = xcd_swz(blockIdx.x, gridDim.x);
    const int bm = (wg / gx) * 128, bn = (wg % gx) * 128;

    auto stage = [&](int k0, int buf) {
        #pragma unroll
        for (int i = 0; i < 4; ++i) {
            int ch = i * 256 + wave * 64 + lane;
            int r = ch >> 3, c8 = ch & 7;
            const unsigned short* ga = A + (size_t)(bm + r) * K + k0 + c8 * 8;
            GLOAD16(ga, (char*)&As[buf][0] + (size_t)(i * 256 + wave * 64) * 16);
            const unsigned short* gb = W + (size_t)(bn + r) * K + k0 + c8 * 8;
            GLOAD16(gb, (char*)&Bs[buf][0] + (size_t)(i * 256 + wave * 64) * 16);
        }
    };

    f32x4 acc[4][4] = {};

    stage(0, 0);
    int cur = 0;

    for (int k0 = 0; k0 < K; k0 += 64) {
        if (k0 + 64 < K) {
            stage(k0 + 64, cur ^ 1);   // 8 loads stay in flight through compute
            VMCNT(8);                  // tile k's 8 loads (mine) complete
        } else {
            VMCNT(0);                  // final tile: drain all
        }
        __builtin_amdgcn_s_barrier();  // everyone's tile-k loads complete

        #pragma unroll
        for (int ks = 0; ks < 2; ++ks) {
            short8 af[4], bf[4];
            #pragma unroll
            for (int mi = 0; mi < 4; ++mi)
                af[mi] = *reinterpret_cast<const short8*>(
                    &As[cur][(wr * 64 + mi * 16 + l15) * 64 + ks * 32 + l4 * 8]);
            #pragma unroll
            for (int ni = 0; ni < 4; ++ni)
                bf[ni] = *reinterpret_cast<const short8*>(
                    &Bs[cur][(wc * 64 + ni * 16 + l15) * 64 + ks * 32 + l4 * 8]);
            #pragma unroll
            for (int mi = 0; mi < 4; ++mi)
                #pragma unroll
                for (int ni = 0; ni < 4; ++ni)
                    acc[mi][ni] = __builtin_amdgcn_mfma_f32_16x16x32_bf16(
                        af[mi], bf[ni], acc[mi][ni], 0, 0, 0);
        }
        __builtin_amdgcn_s_barrier();  // reads of cur done -> next stage may
        cur ^= 1;                      // overwrite it
    }

    #pragma unroll
    for (int ni = 0; ni < 4; ++ni) {
        int col = bn + wc * 64 + ni * 16 + l15;
        float bv = bias[col];
        #pragma unroll
        for (int mi = 0; mi < 4; ++mi) {
            #pragma unroll
            for (int r = 0; r < 4; ++r) {
                int row = bm + wr * 64 + mi * 16 + l4 * 4 + r;
                float v = acc[mi][ni][r] + bv;
                if (OUT_BF16)
                    ((unsigned short*)Cout)[(size_t)row * N + col] = f2b(v);
                else
                    ((float*)Cout)[(size_t)row * N + col] = v;
            }
        }
    }
}

// ---------------------------------------------------------------------------
// Fused QKV GEMM, counted-vmcnt pipeline; W = [Wq;Wk;Wv] [3072][1024].
// Q segment pre-scaled by 1/sqrt(dh) = 0.125 (exact pow2).
// ---------------------------------------------------------------------------
__global__ __launch_bounds__(256)
void gemm_qkv(const unsigned short* __restrict__ A,
              const unsigned short* __restrict__ W,
              const float* __restrict__ bq, const float* __restrict__ bk,
              const float* __restrict__ bv,
              unsigned short* __restrict__ Qb, unsigned short* __restrict__ Kb,
              unsigned short* __restrict__ Vb, int M, int K) {
    __shared__ unsigned short As[2][128 * 64];
    __shared__ unsigned short Bs[2][128 * 64];

    const int tid  = threadIdx.x;
    const int lane = tid & 63, wave = tid >> 6;
    const int l15 = lane & 15, l4 = lane >> 4;
    const int wr = wave >> 1, wc = wave & 1;
    const int gx = 24;   // 3072 / 128
    const int wg = xcd_swz(blockIdx.x, gridDim.x);
    const int bm = (wg / gx) * 128, bn = (wg % gx) * 128;

    auto stage = [&](int k0, int buf) {
        #pragma unroll
        for (int i = 0; i < 4; ++i) {
            int ch = i * 256 + wave * 64 + lane;
            int r = ch >> 3, c8 = ch & 7;
            const unsigned short* ga = A + (size_t)(bm + r) * K + k0 + c8 * 8;
            GLOAD16(ga, (char*)&As[buf][0] + (size_t)(i * 256 + wave * 64) * 16);
            const unsigned short* gb = W + (size_t)(bn + r) * K + k0 + c8 * 8;
            GLOAD16(gb, (char*)&Bs[buf][0] + (size_t)(i * 256 + wave * 64) * 16);
        }
    };

    f32x4 acc[4][4] = {};

    stage(0, 0);
    int cur = 0;

    for (int k0 = 0; k0 < K; k0 += 64) {
        if (k0 + 64 < K) {
            stage(k0 + 64, cur ^ 1);
            VMCNT(8);
        } else {
            VMCNT(0);
        }
        __builtin_amdgcn_s_barrier();

        #pragma unroll
        for (int ks = 0; ks < 2; ++ks) {
            short8 af[4], bf[4];
            #pragma unroll
            for (int mi = 0; mi < 4; ++mi)
                af[mi] = *reinterpret_cast<const short8*>(
                    &As[cur][(wr * 64 + mi * 16 + l15) * 64 + ks * 32 + l4 * 8]);
            #pragma unroll
            for (int ni = 0; ni < 4; ++ni)
                bf[ni] = *reinterpret_cast<const short8*>(
                    &Bs[cur][(wc * 64 + ni * 16 + l15) * 64 + ks * 32 + l4 * 8]);
            #pragma unroll
            for (int mi = 0; mi < 4; ++mi)
                #pragma unroll
                for (int ni = 0; ni < 4; ++ni)
                    acc[mi][ni] = __builtin_amdgcn_mfma_f32_16x16x32_bf16(
                        af[mi], bf[ni], acc[mi][ni], 0, 0, 0);
        }
        __builtin_amdgcn_s_barrier();
        cur ^= 1;
    }

    const int seg = bn >> 10;                 // 0=Q 1=K 2=V
    const float* bp = (seg == 0) ? bq : (seg == 1) ? bk : bv;
    unsigned short* ob = (seg == 0) ? Qb : (seg == 1) ? Kb : Vb;
    const float qs = (seg == 0) ? 0.125f : 1.0f;   // fold 1/sqrt(dh) into Q
    const int cb = bn & 1023;

    #pragma unroll
    for (int ni = 0; ni < 4; ++ni) {
        int col = cb + wc * 64 + ni * 16 + l15;
        float bvv = bp[col];
        #pragma unroll
        for (int mi = 0; mi < 4; ++mi) {
            #pragma unroll
            for (int r = 0; r < 4; ++r) {
                int row = bm + wr * 64 + mi * 16 + l4 * 4 + r;
                ob[(size_t)row * 1024 + col] = f2b((acc[mi][ni][r] + bvv) * qs);
            }
        }
    }
}

// ---------------------------------------------------------------------------
// V transpose prepass: Vb [m][1024] bf16 -> Vtg [(bd*16+h)*64 + dh][L] bf16.
// ---------------------------------------------------------------------------
__global__ __launch_bounds__(256)
void tvt(const unsigned short* __restrict__ Vb, unsigned short* __restrict__ Vtg) {
    __shared__ unsigned short Ts[64 * 64];
    const int tid = threadIdx.x;
    const int blk = blockIdx.x;
    const int lt = blk & 15;
    const int h  = (blk >> 4) & 15;
    const int bd = blk >> 8;
    const int b = bd >> 2, dd = bd & 3;
    const size_t rowbase = (size_t)b * S_;

    #pragma unroll
    for (int i = 0; i < 2; ++i) {
        int ch = i * 256 + tid;
        int lloc = ch >> 3, c8 = ch & 7;
        short8 v = *reinterpret_cast<const short8*>(
            Vb + (rowbase + (size_t)(lt * 64 + lloc) * DIL + dd) * D_ + h * 64 + c8 * 8);
        #pragma unroll
        for (int j = 0; j < 8; ++j) {
            int dh = c8 * 8 + j;
            Ts[dh * 64 + (((lloc >> 3) ^ (dh & 7)) * 8) + (lloc & 7)] = (unsigned short)v[j];
        }
    }
    __syncthreads();

    const size_t obase = ((size_t)(bd * 16 + h) * 64) * L_;
    #pragma unroll
    for (int i = 0; i < 2; ++i) {
        int ch = i * 256 + tid;
        int dh = ch >> 3, c = ch & 7;
        uint4 val = *reinterpret_cast<const uint4*>(&Ts[dh * 64 + ((c ^ (dh & 7)) * 8)]);
        *reinterpret_cast<uint4*>(Vtg + obase + (size_t)dh * L_ + lt * 64 + c * 8) = val;
    }
}

// ---------------------------------------------------------------------------
// MFMA flash attention, swapped-operand form (Q pre-scaled by 0.125).
// Counted-vmcnt pipeline (vmcnt(4)) + setprio around MFMA clusters (T5).
// ---------------------------------------------------------------------------
__global__ __launch_bounds__(256)
void attn_mfma(const unsigned short* __restrict__ Q,
               const unsigned short* __restrict__ K,
               const unsigned short* __restrict__ Vtg,
               unsigned short* __restrict__ O) {
    __shared__ unsigned short Ks[2][64 * 64];   // [key][chunk ^ (key&7)]
    __shared__ unsigned short Vs[2][64 * 64];   // V^T [dh][chunk ^ (dh&7)]
    __shared__ unsigned short Ps[4][1024];      // per-wave P band [q=16][key=64]

    const int tid = threadIdx.x;
    const int lane = tid & 63, wave = tid >> 6;
    const int l15 = lane & 15, l4 = lane >> 4;
    const int blk = xcd_swz(blockIdx.x, gridDim.x);
    const int qt = blk & 15;
    const int h  = (blk >> 4) & 15;
    const int bd = blk >> 8;
    const int b = bd >> 2, dd = bd & 3;
    const size_t rowbase = (size_t)b * S_;
    const int colbase = h * DH_;

    short8 qf[2];
    {
        int q = qt * 64 + wave * 16 + l15;
        const unsigned short* qp =
            Q + (rowbase + (size_t)q * DIL + dd) * D_ + colbase;
        qf[0] = *reinterpret_cast<const short8*>(qp + l4 * 8);
        qf[1] = *reinterpret_cast<const short8*>(qp + 32 + l4 * 8);
    }

    const unsigned short* vbase = Vtg + ((size_t)(bd * 16 + h) * 64) * L_;

    auto stageK = [&](int kt, int buf) {
        #pragma unroll
        for (int i = 0; i < 2; ++i) {
            int key = i * 32 + wave * 8 + (lane >> 3);
            int srcc = (lane & 7) ^ (lane >> 3);      // pre-swizzled source chunk
            const unsigned short* g =
                K + (rowbase + (size_t)(kt * 64 + key) * DIL + dd) * D_ + colbase + srcc * 8;
            GLOAD16(g, (char*)&Ks[buf][0] + (size_t)(i * 256 + wave * 64) * 16);
        }
    };
    auto stageV = [&](int kt, int buf) {
        #pragma unroll
        for (int i = 0; i < 2; ++i) {
            int dh = i * 32 + wave * 8 + (lane >> 3);
            int srcc = (lane & 7) ^ (lane >> 3);
            const unsigned short* g = vbase + (size_t)dh * L_ + kt * 64 + srcc * 8;
            GLOAD16(g, (char*)&Vs[buf][0] + (size_t)(i * 256 + wave * 64) * 16);
        }
    };

    f32x4 oT[4] = {};
    float m_run = -1e30f, l_run = 0.f;

    stageK(0, 0);
    stageV(0, 0);

    constexpr int NT = L_ / 64;
    for (int kt = 0; kt < NT; ++kt) {
        int cur = kt & 1, nxt = cur ^ 1;
        if (kt < NT - 1) {                 // next-tile loads stay in flight
            stageK(kt + 1, nxt);
            stageV(kt + 1, nxt);
            VMCNT(4);                      // tile kt's 4 loads (mine) complete
        } else {
            VMCNT(0);
        }
        __builtin_amdgcn_s_barrier();      // everyone's tile-kt loads complete

        // ---- QK^T (S^T form): lane holds S[q=l15][key = n*16 + l4*4 + r] ----
        f32x4 sT[4];
        __builtin_amdgcn_s_setprio(1);
        #pragma unroll
        for (int n = 0; n < 4; ++n) {
            int row = n * 16 + l15;
            short8 kf0 = *reinterpret_cast<const short8*>(
                &Ks[cur][row * 64 + ((0 * 4 + l4) ^ (l15 & 7)) * 8]);
            short8 kf1 = *reinterpret_cast<const short8*>(
                &Ks[cur][row * 64 + ((1 * 4 + l4) ^ (l15 & 7)) * 8]);
            f32x4 z = {0.f, 0.f, 0.f, 0.f};
            z = __builtin_amdgcn_mfma_f32_16x16x32_bf16(kf0, qf[0], z, 0, 0, 0);
            z = __builtin_amdgcn_mfma_f32_16x16x32_bf16(kf1, qf[1], z, 0, 0, 0);
            sT[n] = z;   // Q pre-scaled by 1/sqrt(dh)
        }
        __builtin_amdgcn_s_setprio(0);

        // ---- lane-local online softmax (q = l15) ----
        float mx = -1e30f;
        #pragma unroll
        for (int n = 0; n < 4; ++n)
            #pragma unroll
            for (int r = 0; r < 4; ++r) mx = fmaxf(mx, sT[n][r]);
        mx = fmaxf(mx, __shfl_xor(mx, 16));
        mx = fmaxf(mx, __shfl_xor(mx, 32));
        float m_new = fmaxf(m_run, mx);
        float scale = __expf(m_run - m_new);
        float p[4][4], rsum = 0.f;
        #pragma unroll
        for (int n = 0; n < 4; ++n)
            #pragma unroll
            for (int r = 0; r < 4; ++r) {
                p[n][r] = __expf(sT[n][r] - m_new);
                rsum += p[n][r];
            }
        rsum += __shfl_xor(rsum, 16);
        rsum += __shfl_xor(rsum, 32);
        l_run = l_run * scale + rsum;
        m_run = m_new;
        #pragma unroll
        for (int nd = 0; nd < 4; ++nd) oT[nd] *= scale;

        // ---- P -> per-wave swizzled LDS band ----
        #pragma unroll
        for (int n = 0; n < 4; ++n) {
            uint2 w;
            w.x = pkbf(p[n][0], p[n][1]);
            w.y = pkbf(p[n][2], p[n][3]);
            int c = n * 2 + (l4 >> 1);
            int pc = c ^ (l15 & 7);
            *reinterpret_cast<uint2*>(&Ps[wave][l15 * 64 + pc * 8 + (l4 & 1) * 4]) = w;
        }
        short8 pb0 = *reinterpret_cast<const short8*>(
            &Ps[wave][l15 * 64 + ((0 * 4 + l4) ^ (l15 & 7)) * 8]);
        short8 pb1 = *reinterpret_cast<const short8*>(
            &Ps[wave][l15 * 64 + ((1 * 4 + l4) ^ (l15 & 7)) * 8]);

        // ---- PV: O^T += V^T . P ----
        __builtin_amdgcn_s_setprio(1);
        #pragma unroll
        for (int ks = 0; ks < 2; ++ks) {
            short8 pb = ks ? pb1 : pb0;
            #pragma unroll
            for (int nd = 0; nd < 4; ++nd) {
                short8 vf = *reinterpret_cast<const short8*>(
                    &Vs[cur][(nd * 16 + l15) * 64 + ((ks * 4 + l4) ^ (l15 & 7)) * 8]);
                oT[nd] = __builtin_amdgcn_mfma_f32_16x16x32_bf16(vf, pb, oT[nd], 0, 0, 0);
            }
        }
        __builtin_amdgcn_s_setprio(0);

        __builtin_amdgcn_s_barrier();      // reads of cur done -> next stage
    }                                      // may overwrite it

    // ---- epilogue: per-wave transpose band (reuse Ps) + coalesced store ----
    unsigned short* Es = &Ps[0][0];
    float inv = 1.f / l_run;
    #pragma unroll
    for (int nd = 0; nd < 4; ++nd) {
        uint2 w;
        w.x = pkbf(oT[nd][0] * inv, oT[nd][1] * inv);
        w.y = pkbf(oT[nd][2] * inv, oT[nd][3] * inv);
        int chunk = nd * 2 + (l4 >> 1);
        int pc = chunk ^ (l15 & 7);
        *reinterpret_cast<uint2*>(&Es[wave * 1024 + l15 * 64 + pc * 8 + (l4 & 1) * 4]) = w;
    }
    __syncthreads();
    {
        int row = lane >> 2;              // q_local 0..15
        int q = qt * 64 + wave * 16 + row;
        unsigned short* op = O + (rowbase + (size_t)q * DIL + dd) * D_ + colbase;
        #pragma unroll
        for (int i = 0; i < 2; ++i) {
            int c = (lane & 3) * 2 + i;
            int pc = c ^ (row & 7);
            uint4 val = *reinterpret_cast<const uint4*>(&Es[wave * 1024 + row * 64 + pc * 8]);
            *reinterpret_cast<uint4*>(op + c * 8) = val;
        }
    }
}

// ---------------------------------------------------------------------------
// final = LayerNorm(atted + x) * gamma + beta
// ---------------------------------------------------------------------------
__global__ __launch_bounds__(256)
void add_ln(const float* __restrict__ atted, const float* __restrict__ x,
            const float* __restrict__ gamma, const float* __restrict__ beta,
            float* __restrict__ out) {
    __shared__ float red[8];
    const int tid = threadIdx.x;
    const size_t base = (size_t)blockIdx.x * D_;

    float4 a  = *reinterpret_cast<const float4*>(atted + base + tid * 4);
    float4 xv = *reinterpret_cast<const float4*>(x + base + tid * 4);
    float v0 = a.x + xv.x, v1 = a.y + xv.y, v2 = a.z + xv.z, v3 = a.w + xv.w;

    float s = v0 + v1 + v2 + v3;
    #pragma unroll
    for (int o = 1; o < 64; o <<= 1) s += __shfl_xor(s, o);
    if ((tid & 63) == 0) red[tid >> 6] = s;
    __syncthreads();
    float mean = (red[0] + red[1] + red[2] + red[3]) * (1.0f / D_);

    float d0 = v0 - mean, d1 = v1 - mean, d2 = v2 - mean, d3 = v3 - mean;
    float sq = d0 * d0 + d1 * d1 + d2 * d2 + d3 * d3;
    #pragma unroll
    for (int o = 1; o < 64; o <<= 1) sq += __shfl_xor(sq, o);
    if ((tid & 63) == 0) red[4 + (tid >> 6)] = sq;
    __syncthreads();
    float var = (red[4] + red[5] + red[6] + red[7]) * (1.0f / D_);
    float inv = rsqrtf(var + 1e-5f);

    float4 g  = *reinterpret_cast<const float4*>(gamma + tid * 4);
    float4 bb = *reinterpret_cast<const float4*>(beta + tid * 4);
    float4 o4;
    o4.x = d0 * inv * g.x + bb.x;
    o4.y = d1 * inv * g.y + bb.y;
    o4.z = d2 * inv * g.z + bb.z;
    o4.w = d3 * inv * g.w + bb.w;
    *reinterpret_cast<float4*>(out + base + tid * 4) = o4;
}

// ---------------------------------------------------------------------------
extern "C" void kernel_launch(void* const* d_in, const int* in_sizes, int n_in,
                              void* d_out, int out_size, void* d_ws, size_t ws_size,
                              hipStream_t stream) {
    const float* x     = (const float*)d_in[0];
    const float* Wq    = (const float*)d_in[1];
    const float* bq    = (const float*)d_in[2];
    const float* Wk    = (const float*)d_in[3];
    const float* bk    = (const float*)d_in[4];
    const float* Wv    = (const float*)d_in[5];
    const float* bv    = (const float*)d_in[6];
    const float* Wf    = (const float*)d_in[7];
    const float* bf    = (const float*)d_in[8];
    const float* gamma = (const float*)d_in[9];
    const float* beta  = (const float*)d_in[10];

    float* final_out = (float*)d_out;               // (B,S,D) fp32
    float* atted     = final_out + (size_t)M_ * D_; // (B,S,D) fp32

    // Workspace (bf16): 16 + 8 + 48 + 16 = 88 MB (<100.7 MB proven in R1)
    unsigned short* xb  = (unsigned short*)d_ws;    // reused as ctxb after QKV
    unsigned short* Wqb = xb  + (size_t)M_ * D_;
    unsigned short* Wkb = Wqb + (size_t)D_ * D_;
    unsigned short* Wvb = Wkb + (size_t)D_ * D_;
    unsigned short* Wfb = Wvb + (size_t)D_ * D_;
    unsigned short* Qb  = Wfb + (size_t)D_ * D_;
    unsigned short* Kb  = Qb  + (size_t)M_ * D_;
    unsigned short* Vb  = Kb  + (size_t)M_ * D_;
    unsigned short* Vtg = Vb  + (size_t)M_ * D_;    // [(bd*16+h)*64+dh][L]
    unsigned short* ctxb = xb;

    conv_f2b<<<dim3(M_ * D_ / 4 / 256), 256, 0, stream>>>(x, xb, M_ * D_ / 4);
    conv_w4<<<dim3(4096), 256, 0, stream>>>(Wq, Wk, Wv, Wf, Wqb);

    gemm_qkv<<<dim3((3072 / 128) * (M_ / 128)), 256, 0, stream>>>(
        xb, Wqb, bq, bk, bv, Qb, Kb, Vb, M_, D_);

    tvt<<<dim3(DIL * B_ * H_ * (L_ / 64)), 256, 0, stream>>>(Vb, Vtg);

    attn_mfma<<<dim3(DIL * B_ * H_ * (L_ / 64)), 256, 0, stream>>>(Qb, Kb, Vtg, ctxb);

    gemm_mfma<0><<<dim3((D_ / 128) * (M_ / 128)), 256, 0, stream>>>(
        ctxb, Wfb, bf, atted, M_, D_, D_);

    add_ln<<<dim3(M_), 256, 0, stream>>>(atted, x, gamma, beta, final_out);
}